// Round 1
// 701.806 us; speedup vs baseline: 1.0721x; 1.0721x over previous
//
#include <hip/hip_runtime.h>

typedef __bf16  bf16x8 __attribute__((ext_vector_type(8)));
typedef float   f32x4  __attribute__((ext_vector_type(4)));

union ABCast { uint4 u; bf16x8 f; };

__device__ __forceinline__ unsigned short f2bf(float x) {
  unsigned u = __builtin_bit_cast(unsigned, x);
  u += 0x7FFFu + ((u >> 16) & 1u);          // round-to-nearest-even
  return (unsigned short)(u >> 16);
}

#define IMG_W  512
#define IMG_HW (512 * 512)
#define TILE_R 16
#define TILE_C 32
#define TIN_H  18
#define TIN_W  34
#define PXS    40   // ushorts per LDS pixel: 32 channels + 8 pad (80 B, 16B-aligned stride)

// Pre-pack OIHW fp32 weights into per-lane B-fragment order for mfma_f32_16x16x32_bf16:
// B[k=c][n=oc_local], lane = ((c>>3)<<4) | (oc&15), j = c&7, per (tap, oc-half).
__global__ void pack_weights(const float* __restrict__ w, unsigned short* __restrict__ wsb) {
  int f = blockIdx.x * 256 + threadIdx.x;
  if (f < 9216) {
    int kw = f % 3, kh = (f / 3) % 3, c = (f / 9) % 32, oc = f / 288;
    int tap = kh * 3 + kw, nh = oc >> 4;
    int lane = ((c >> 3) << 4) | (oc & 15);
    int j = c & 7;
    wsb[(((tap * 2 + nh) * 64) + lane) * 8 + j] = f2bf(w[f]);
  }
}

// Block: 256 threads = 4 waves; computes 16 rows x 32 cols x 32 oc.
// wave: nh = oc-half (0/1), rq = row-half (0/1): 8 rows x 32 cols x 16 oc
//       = 16 M-frags (8 rows x 2 col-halves) x 1 N-frag, 9 taps.
// Epilogue transposes acc through LDS so each global store instruction writes
// eight full 128B lines (8 consecutive lanes per (oc,row) segment) -- avoids
// the 16-plane-scatter store pattern that caused ~3.7x write amplification.
__global__ __launch_bounds__(256, 3)
void conv3x3(const float* __restrict__ x, const float* __restrict__ bias,
             const unsigned short* __restrict__ wsb, float* __restrict__ out) {
  __shared__ unsigned short smem[TIN_H * TIN_W * PXS]; // 612 px * 80 B = 48960 B

  const int b    = blockIdx.x;
  const int n    = b & 7;        // image per XCD (round-robin heuristic)
  const int t    = b >> 3;
  const int tr   = t >> 4;       // 0..31 row tile
  const int tc   = t & 15;       // 0..15 col tile
  const int tid  = threadIdx.x;
  const int lane = tid & 63;
  const int wave = tid >> 6;
  const int nh   = wave & 1;
  const int rq   = wave >> 1;

  const float* xn = x + (size_t)n * 32 * IMG_HW;

  // B fragments: 9 coalesced 16B loads from pre-packed ws (L2-warm), kept in VGPRs.
  bf16x8 bfrag[9];
  {
    const uint4* wp = (const uint4*)wsb;
    #pragma unroll
    for (int tap = 0; tap < 9; ++tap) {
      ABCast cv; cv.u = wp[(tap * 2 + nh) * 64 + lane];
      bfrag[tap] = cv.f;
    }
  }
  const float bs = bias[nh * 16 + (lane & 15)];

  // ---- Stage input tile (18x34 px, 32 ch) fp32 -> bf16 into LDS [px][ch] ----
  const int r0 = tr * TILE_R - 1;
  const int c0 = tc * TILE_C - 1;
  #pragma unroll
  for (int it = 0; it < 3; ++it) {
    int p = tid + it * 256;
    if (p < TIN_H * TIN_W) {
      int pr = p / TIN_W, pc = p - pr * TIN_W;
      int gr = r0 + pr,  gc = c0 + pc;
      float v[32];
      if ((unsigned)gr < 512u && (unsigned)gc < 512u) {
        const float* src = xn + (size_t)gr * IMG_W + gc;
        #pragma unroll
        for (int c = 0; c < 32; ++c) v[c] = src[(size_t)c * IMG_HW];
      } else {
        #pragma unroll
        for (int c = 0; c < 32; ++c) v[c] = 0.0f;
      }
      uint2* dst = (uint2*)(smem + p * PXS);
      #pragma unroll
      for (int k = 0; k < 8; ++k) {
        unsigned lo = (unsigned)f2bf(v[4 * k])     | ((unsigned)f2bf(v[4 * k + 1]) << 16);
        unsigned hi = (unsigned)f2bf(v[4 * k + 2]) | ((unsigned)f2bf(v[4 * k + 3]) << 16);
        dst[k] = make_uint2(lo, hi);
      }
    }
  }
  __syncthreads();

  // ---- MFMA main loop ----
  f32x4 acc[16];
  #pragma unroll
  for (int i = 0; i < 16; ++i) acc[i] = (f32x4){0.f, 0.f, 0.f, 0.f};

  // A-frag: lane reads A[m=lane&15][k=(lane>>4)*8+j] -> px = base + m, ch-group = lane>>4
  const unsigned short* abase = smem + (lane & 15) * PXS + (lane >> 4) * 8;

  #pragma unroll
  for (int kh = 0; kh < 3; ++kh) {
    #pragma unroll
    for (int kw = 0; kw < 3; ++kw) {
      const bf16x8 bf = bfrag[kh * 3 + kw];
      #pragma unroll
      for (int i = 0; i < 8; ++i) {
        #pragma unroll
        for (int ch = 0; ch < 2; ++ch) {
          int px = (rq * 8 + i + kh) * TIN_W + ch * 16 + kw;
          ABCast cv; cv.u = *(const uint4*)(abase + px * PXS);
          acc[i * 2 + ch] =
              __builtin_amdgcn_mfma_f32_16x16x32_bf16(cv.f, bf, acc[i * 2 + ch], 0, 0, 0);
        }
      }
    }
  }

  // ---- Epilogue: transpose through LDS (reuse smem), then full-line stores ----
  // Pair p = rg*32 + oc, rg in 0..7 (row group), oc in 0..31; each pair owns a
  // 32-float (128B) row segment stored as 8 xor-swizzled 16B chunks:
  //   chunk c lives at slot (c ^ (p&7))  -> both phases hit the 8-cycle LDS floor.
  float* sf = (float*)smem;               // need 8192 floats = 32 KB per pass
  const int ocl = lane & 15, q = lane >> 4;
  float* outn = out + (size_t)n * 32 * IMG_HW;
  __syncthreads();                        // all waves done reading input tile

  #pragma unroll
  for (int P = 0; P < 2; ++P) {
    // Write phase: all 4 waves write acc i = P*4..P*4+3 (rows rq*8 + P*4 + ii).
    #pragma unroll
    for (int ii = 0; ii < 4; ++ii) {
      int i = P * 4 + ii;
      int p = (rq * 4 + ii) * 32 + nh * 16 + ocl;
      #pragma unroll
      for (int ch = 0; ch < 2; ++ch) {
        int slot = (ch * 4 + q) ^ (p & 7);
        f32x4 v = acc[i * 2 + ch];
        v += bs;
        *(f32x4*)(sf + p * 32 + slot * 4) = v;
      }
    }
    __syncthreads();
    // Read phase: 8 consecutive lanes cover one (oc,row) 128B segment.
    {
      const int s = tid >> 3, off = tid & 7;   // s = oc (0..31), off = col chunk
      #pragma unroll
      for (int it = 0; it < 8; ++it) {
        int p = it * 32 + s;                   // rg = it, oc = s
        f32x4 v = *(const f32x4*)(sf + p * 32 + ((off ^ (p & 7)) * 4));
        int row = tr * TILE_R + (it >> 2) * 8 + P * 4 + (it & 3);
        *(f32x4*)(outn + (size_t)s * IMG_HW + (size_t)row * IMG_W
                  + tc * TILE_C + off * 4) = v;
      }
    }
    if (P == 0) __syncthreads();               // pass-0 readers done before pass-1 writes
  }
}

extern "C" void kernel_launch(void* const* d_in, const int* in_sizes, int n_in,
                              void* d_out, int out_size, void* d_ws, size_t ws_size,
                              hipStream_t stream) {
  const float* x    = (const float*)d_in[0];
  const float* w    = (const float*)d_in[1];
  const float* bias = (const float*)d_in[2];
  float* out = (float*)d_out;
  unsigned short* wsb = (unsigned short*)d_ws;

  hipLaunchKernelGGL(pack_weights, dim3(36), dim3(256), 0, stream, w, wsb);
  hipLaunchKernelGGL(conv3x3, dim3(8 * 32 * 16), dim3(256), 0, stream, x, bias, wsb, out);
}